// Round 13
// baseline (762.497 us; speedup 1.0000x reference)
//
#include <hip/hip_runtime.h>
#include <hip/hip_bf16.h>
#include <stdint.h>

#define M_ROWS 4096
#define N_REFS 32768
#define DIM    512
#define DIMB   256                 // bytes per row in fp4 (512 * 0.5)
#define NSPLIT 32
#define BM     128
#define CHUNK  128
#define SLICE  (N_REFS / NSPLIT)   // 1024
#define NCHUNKS (SLICE / CHUNK)    // 8
#define NKT    4                   // 4 K-tiles of 128 fp4 elems (64B)
#define NSTEP  (NCHUNKS * NKT)     // 32 flattened steps
#define SET    16384               // ring set: A 8KB + B 8KB

typedef __attribute__((ext_vector_type(4))) int   i32x4;
typedef __attribute__((ext_vector_type(8))) int   i32x8;
typedef __attribute__((ext_vector_type(4))) float f32x4;

#define C_L2E2 2.0813689810056077f   // (log2 e)^2: exp(-sqrt(t)) == exp2(-sqrt(C*t))

// fp32 -> OCP e2m1 (fp4) code 0..7 = {0,.5,1,1.5,2,3,4,6}, sign in bit 3.
__device__ __forceinline__ uint32_t f32_to_e2m1(float f) {
  float a = fabsf(f);
  uint32_t s = (__float_as_uint(f) >> 28) & 0x8u;
  uint32_t c = (a >= 0.25f) + (a >= 0.75f) + (a >= 1.25f) + (a >= 1.75f)
             + (a >= 2.5f)  + (a >= 3.5f)  + (a >= 5.0f);
  return s | c;
}

// One block per row: fp32 row -> fp4 nibbles (k ascending from LSB);
// sum-of-squares from EXACT fp32, pre-scaled by C_L2E2.
__global__ void prep_rows_fp4(const float* __restrict__ src, uint8_t* __restrict__ dst,
                              float* __restrict__ sq) {
  int row = blockIdx.x;
  int t = threadIdx.x;                       // 128 threads, 4 elems each
  const float4* s = (const float4*)(src + (size_t)row * DIM);
  float4 v = s[t];
  uint32_t p = f32_to_e2m1(v.x) | (f32_to_e2m1(v.y) << 4)
             | (f32_to_e2m1(v.z) << 8) | (f32_to_e2m1(v.w) << 12);
  ((uint16_t*)(dst + (size_t)row * DIMB))[t] = (uint16_t)p;
  float ss = v.x * v.x + v.y * v.y + v.z * v.z + v.w * v.w;
  #pragma unroll
  for (int d = 32; d >= 1; d >>= 1) ss += __shfl_down(ss, d, 64);
  __shared__ float wsum[2];
  int w = t >> 6, lane = t & 63;
  if (lane == 0) wsum[w] = ss;
  __syncthreads();
  if (t == 0) sq[row] = C_L2E2 * (wsum[0] + wsum[1]);
}

// MX-fp4 port of the R12 frame: 16x16x128 f8f6f4 with FMT=4 (e2m1), unit
// scales. Tiles are 128 rows x 64B -> ring-4 LDS (4x16KB=64KB) with counted
// vmcnt(4) = depth-2 prefetch (fixes R12's depth-1 HBM exposure). Per-frag
// read = ONE ds_read_b128 (LDS reads halved vs fp8); slot swizzle
// s = l4 ^ ((row>>1)&3) -> worst 2-way bank aliasing (free, m136); staging
// source pre-permuted by the same involution (rule #21). Epilogue metadata
// (cr2/yref) prefetched at kt==2 so the kt==3 epilogue's loads don't drain
// the two in-flight stages. Epilogue/acc layout identical to R10/R12.
__global__ __launch_bounds__(256, 2) void ask_main(
    const uint8_t* __restrict__ xf4, const uint8_t* __restrict__ rf4,
    const float* __restrict__ cx2, const float* __restrict__ cr2,
    const int* __restrict__ y, const int* __restrict__ yref,
    float* __restrict__ totG, float* __restrict__ matchG)
{
  __shared__ unsigned char smem[4 * SET];    // 64 KB ring

  const int tid  = threadIdx.x;
  const int w    = tid >> 6, lane = tid & 63;
  const int wr   = w >> 1,  wc   = w & 1;
  const int l15  = lane & 15, l4 = lane >> 4;

  const int bm       = blockIdx.x * BM;
  const int colstart = blockIdx.y * SLICE;

  // staging: thread covers (local row = c*64 + tid>>2, linear slot q = tid&3);
  // source slot g = q ^ ((row>>1)&3) = (tid&3) ^ ((tid>>3)&3).
  const int strow = tid >> 2;                              // 0..63
  const int gsl   = (tid & 3) ^ ((tid >> 3) & 3);
  const uint8_t* aS = xf4 + (size_t)(bm + strow) * DIMB + gsl * 16;
  const uint8_t* bS = rf4 + (size_t)(colstart + strow) * DIMB + gsl * 16;

#define GLL(srcp, dstoff)                                                        \
  __builtin_amdgcn_global_load_lds(                                              \
      (const __attribute__((address_space(1))) void*)(srcp),                     \
      (__attribute__((address_space(3))) void*)(smem + (dstoff)), 16, 0, 0)

  // stage step gidx into ring set (gidx&3): A 2 chunks of 64 rows, B same
#define STAGE(gidx)                                                              \
  { const int ch_ = (gidx) >> 2, dk_ = ((gidx) & 3) * 64, s_ = ((gidx) & 3) * SET; \
    const uint8_t* gB_ = bS + (size_t)ch_ * CHUNK * DIMB + dk_;                  \
    GLL(aS + dk_,                    s_ + 0 * 4096 + tid * 16);                  \
    GLL(aS + dk_ + 64 * DIMB,        s_ + 1 * 4096 + tid * 16);                  \
    GLL(gB_,                         s_ + 8192 + 0 * 4096 + tid * 16);           \
    GLL(gB_ + 64 * DIMB,             s_ + 8192 + 1 * 4096 + tid * 16); }

  // fragment reads: row = base + f*16 + l15 (64B rows), ONE b128 at
  // slot s = l4 ^ ((row>>1)&3); (row>>1)&3 == (l15>>1)&3 since base%16==0.
  const int sl = (l4 ^ ((l15 >> 1) & 3)) * 16;
  int aoff[4], boff[4];
  #pragma unroll
  for (int i = 0; i < 4; ++i) {
    aoff[i] = (wr * 64 + i * 16 + l15) * 64 + sl;
    boff[i] = (wc * 64 + i * 16 + l15) * 64 + sl + 8192;
  }

  float tot[16], mat[16];
  #pragma unroll
  for (int i = 0; i < 16; ++i) { tot[i] = 0.f; mat[i] = 0.f; }

  f32x4 acc[4][4];
  const f32x4 fz = {0.f, 0.f, 0.f, 0.f};
  const i32x4 iz = {0, 0, 0, 0};

  float r2cP[4]; int clsP[4];                // epilogue metadata, prefetched @kt2

  // ---- prologue: stage tiles 0,1; wait tile0 (4 of 8 outstanding) ----
  STAGE(0);
  STAGE(1);
  asm volatile("s_waitcnt vmcnt(4)" ::: "memory");
  __builtin_amdgcn_s_barrier();

  #pragma unroll
  for (int g = 0; g < NSTEP; ++g) {
    const int kt = g & 3, ch = g >> 2;
    const int so = (g & 3) * SET;

    if (kt == 2) {
      // prefetch epilogue metadata for this chunk (issued BEFORE this step's
      // STAGE so the kt3 use-wait keeps both in-flight stages alive)
      const int colb = colstart + ch * CHUNK;
      #pragma unroll
      for (int ni = 0; ni < 4; ++ni) {
        int cg = colb + wc * 64 + ni * 16 + l15;
        r2cP[ni] = cr2[cg];
        clsP[ni] = yref[cg];
      }
    }
    if (g + 2 < NSTEP) { STAGE(g + 2); }

    if (kt == 0) {
      #pragma unroll
      for (int mi = 0; mi < 4; ++mi)
        #pragma unroll
        for (int ni = 0; ni < 4; ++ni) acc[mi][ni] = fz;
    }

    const unsigned char* pS = smem + so;
    i32x8 bfr[4];
    #pragma unroll
    for (int ni = 0; ni < 4; ++ni) {
      i32x4 lo = *(const i32x4*)(pS + boff[ni]);
      bfr[ni] = __builtin_shufflevector(lo, iz, 0, 1, 2, 3, 4, 5, 6, 7);
    }
    #pragma unroll
    for (int mi = 0; mi < 4; ++mi) {
      i32x4 lo = *(const i32x4*)(pS + aoff[mi]);
      i32x8 afr = __builtin_shufflevector(lo, iz, 0, 1, 2, 3, 4, 5, 6, 7);
      #pragma unroll
      for (int ni = 0; ni < 4; ++ni)
        acc[mi][ni] = __builtin_amdgcn_mfma_scale_f32_16x16x128_f8f6f4(
            afr, bfr[ni], acc[mi][ni],
            4, 4,                      // cbsz=fp4(e2m1), blgp=fp4(e2m1)
            0, 0x7F7F7F7F,             // A scales = 1.0 (E8M0 127)
            0, 0x7F7F7F7F);            // B scales = 1.0
    }

    if (kt == 3) {
      // fused epilogue (chunk ch): e = exp2(-sqrt(cx2 + cr2 - 2c*dot))
      #pragma unroll
      for (int mi = 0; mi < 4; ++mi) {
        #pragma unroll
        for (int r = 0; r < 4; ++r) {
          int row = bm + wr * 64 + mi * 16 + l4 * 4 + r;
          float xr = cx2[row];
          int   yy = y[row];
          float tsum = 0.f, msum = 0.f;
          #pragma unroll
          for (int ni = 0; ni < 4; ++ni) {
            float t = fmaf(-2.0f * C_L2E2, acc[mi][ni][r], xr + r2cP[ni]);
            t = fmaxf(t, 0.0f);
            float d = __builtin_amdgcn_sqrtf(t);
            float e = __builtin_amdgcn_exp2f(-d);       // neg = free src modifier
            tsum += e;
            msum = fmaf(e, (clsP[ni] == yy) ? 1.0f : 0.0f, msum);
          }
          tot[mi * 4 + r] += tsum;
          mat[mi * 4 + r] += msum;
        }
      }
    }

    // boundary: tile g+1 must be resident; keep depth-2 in flight
    if (g + 2 < NSTEP) {
      if (kt == 2) { asm volatile("s_waitcnt vmcnt(12)" ::: "memory"); }
      else         { asm volatile("s_waitcnt vmcnt(4)"  ::: "memory"); }
    } else if (g == NSTEP - 2) {
      asm volatile("s_waitcnt vmcnt(8)" ::: "memory");   // stage(31) landed
    }
    if (g < NSTEP - 1) __builtin_amdgcn_s_barrier();
  }

  // reduce across the 16 lanes (l15) sharing each row, then merge globally
  #pragma unroll
  for (int i = 0; i < 16; ++i) {
    float t = tot[i], m = mat[i];
    #pragma unroll
    for (int d = 1; d <= 8; d <<= 1) {
      t += __shfl_xor(t, d, 64);
      m += __shfl_xor(m, d, 64);
    }
    if (l15 == 0) {
      int row = bm + wr * 64 + (i >> 2) * 16 + l4 * 4 + (i & 3);
      atomicAdd(&totG[row], t);
      atomicAdd(&matchG[row], m);
    }
  }
#undef GLL
#undef STAGE
}

__global__ void finalize_loss(const float* __restrict__ totG, const float* __restrict__ matchG,
                              float* __restrict__ out) {
  __shared__ float red[256];
  int t = threadIdx.x;
  float s = 0.f;
  for (int r = t; r < M_ROWS; r += 256)
    s += logf(matchG[r] / totG[r] + 1e-6f);
  red[t] = s;
  __syncthreads();
  for (int off = 128; off >= 1; off >>= 1) {
    if (t < off) red[t] += red[t + off];
    __syncthreads();
  }
  if (t == 0) out[0] = -red[0] / (float)M_ROWS;
}

extern "C" void kernel_launch(void* const* d_in, const int* in_sizes, int n_in,
                              void* d_out, int out_size, void* d_ws, size_t ws_size,
                              hipStream_t stream) {
  const float* x    = (const float*)d_in[0];
  const float* xref = (const float*)d_in[1];
  const int*   y    = (const int*)d_in[2];
  const int*   yref = (const int*)d_in[3];
  float* out = (float*)d_out;

  uint8_t* ws = (uint8_t*)d_ws;
  uint8_t* xf4    = ws;                                 //  1 MB
  uint8_t* rf4    = ws + 1048576;                       //  8 MB
  float*   cx2    = (float*)(ws + 9437184);             // 16 KB (pre-scaled)
  float*   cr2    = (float*)(ws + 9453568);             // 128 KB (pre-scaled)
  float*   totG   = (float*)(ws + 9584640);             // 16 KB
  float*   matchG = (float*)(ws + 9601024);             // 16 KB

  hipMemsetAsync(totG, 0, 2 * M_ROWS * sizeof(float), stream);

  prep_rows_fp4<<<M_ROWS, 128, 0, stream>>>(x, xf4, cx2);
  prep_rows_fp4<<<N_REFS, 128, 0, stream>>>(xref, rf4, cr2);
  ask_main<<<dim3(M_ROWS / BM, NSPLIT), 256, 0, stream>>>(xf4, rf4, cx2, cr2, y, yref, totG, matchG);
  finalize_loss<<<1, 256, 0, stream>>>(totG, matchG, out);
}

// Round 14
// 203.115 us; speedup vs baseline: 3.7540x; 3.7540x over previous
//
#include <hip/hip_runtime.h>
#include <hip/hip_bf16.h>
#include <stdint.h>

#define M_ROWS 4096
#define N_REFS 32768
#define DIM    512
#define NSPLIT 32
#define BM     128
#define CHUNK  128
#define SLICE  (N_REFS / NSPLIT)   // 1024
#define NCHUNKS (SLICE / CHUNK)    // 8
#define NKT    (DIM / 128)         // 4 K-tiles of 128 fp8 elems
#define NSTEP  (NCHUNKS * NKT)     // 32 flattened pipeline steps
#define ABUF   16384               // A tile: 128 rows x 128B

typedef __attribute__((ext_vector_type(4))) int   i32x4;
typedef __attribute__((ext_vector_type(8))) int   i32x8;
typedef __attribute__((ext_vector_type(4))) float f32x4;

#define C_L2E2 2.0813689810056077f   // (log2 e)^2: exp(-sqrt(t)) == exp2(-sqrt(C*t))

// fp32 -> OCP e4m3fn, RNE, saturating. Bit-exact, no builtins.
__device__ __forceinline__ uint32_t f32_to_e4m3(float f) {
  uint32_t u = __float_as_uint(f);
  uint32_t s = (u >> 24) & 0x80u;
  float a = fabsf(f);
  if (a > 448.f) a = 448.f;                  // e4m3fn has no inf; saturate
  uint32_t b;
  if (a >= 0.015625f) {                      // normal range (>= 2^-6)
    uint32_t v = __float_as_uint(a);
    v += 0x7FFFFu + ((v >> 20) & 1u);        // RNE at mantissa bit 20
    int e = (int)(v >> 23) - 127;
    uint32_t m = (v >> 20) & 7u;
    b = (uint32_t)((e + 7) << 3) | m;
    if (b > 0x7Eu) b = 0x7Eu;                // clamp to 448
  } else {
    b = (uint32_t)(a * 512.f + 0.5f);        // subnormal grid 2^-9 (m<=8 ok)
  }
  return s | b;
}

// Fused prep (one launch): rows 0..M-1 -> x, rows M.. -> xref.
// fp32 row -> e4m3 packed; sum-of-squares PRE-SCALED by C_L2E2.
__global__ void prep_all_fp8(const float* __restrict__ x, const float* __restrict__ xref,
                             uint8_t* __restrict__ xf8, uint8_t* __restrict__ rf8,
                             float* __restrict__ cx2, float* __restrict__ cr2) {
  const int b = blockIdx.x;
  const float* src; uint8_t* dst; float* sq; int row;
  if (b < M_ROWS) { src = x;    dst = xf8; sq = cx2; row = b; }
  else            { src = xref; dst = rf8; sq = cr2; row = b - M_ROWS; }
  int t = threadIdx.x;                       // 256 threads, 2 elems each
  const float2* s = (const float2*)(src + (size_t)row * DIM);
  float2 v = s[t];
  uint32_t p = f32_to_e4m3(v.x) | (f32_to_e4m3(v.y) << 8);
  ((uint16_t*)(dst + (size_t)row * DIM))[t] = (uint16_t)p;
  float ss = v.x * v.x + v.y * v.y;
  #pragma unroll
  for (int d = 32; d >= 1; d >>= 1) ss += __shfl_down(ss, d, 64);
  __shared__ float wsum[4];
  int w = t >> 6, lane = t & 63;
  if (lane == 0) wsum[w] = ss;
  __syncthreads();
  if (t == 0) sq[row] = C_L2E2 * (wsum[0] + wsum[1] + wsum[2] + wsum[3]);
}

// R12 frame with B taken OUT of LDS (B has zero reuse within a block beyond
// the in-register bfr hold; A has 8x reuse and stays gll-staged). LDS = A
// double-buffer 2x16KB = 32KB -> 4 blocks/CU (2x the TLP that R12's 64KB
// capped). B-fragment loads: 4 held row-pointers + imm offsets (kt*128,+16).
// Dispatch-order XCD locality: XCD k runs 32 mtiles of one nsl slice at a
// time -> B slice (512KB) + A (2MB) L2-resident. A swizzle/read offsets
// bit-identical to R12 (measured conflict-free).
__global__ __launch_bounds__(256, 2) void ask_main(
    const uint8_t* __restrict__ xf8, const uint8_t* __restrict__ rf8,
    const float* __restrict__ cx2, const float* __restrict__ cr2,
    const int* __restrict__ y, const int* __restrict__ yref,
    float* __restrict__ totG, float* __restrict__ matchG)
{
  __shared__ unsigned char smem[2 * ABUF];   // A only: [buf][128 x 128B]

  const int tid  = threadIdx.x;
  const int w    = tid >> 6, lane = tid & 63;
  const int wr   = w >> 1,  wc   = w & 1;
  const int l15  = lane & 15, l4 = lane >> 4;

  // XCD-locality swizzle: wg -> xcd = wg&7 (dispatch round-robin), i = wg>>3.
  // XCD k sequentially runs nsl = 4k + (i>>5), mtile = i&31 -> one 512KB
  // B-slice x all 32 mtiles at a time, L2-resident. Bijective for 1024 wgs.
  const int wg    = blockIdx.x;
  const int mtile = (wg >> 3) & 31;
  const int nsl   = (wg & 7) * 4 + (wg >> 8);
  const int bm       = mtile * BM;
  const int colstart = nsl * SLICE;

  // A staging (R12-identical): srow = w*8 + lane>>3, linear slot q = lane&7;
  // source slot g: e = q ^ (row&7); g = e<4 ? 2e : 2(e&3)+1  (rule #21).
  const int srow = w * 8 + (lane >> 3);
  const int qsl  = lane & 7;
  const int esl  = qsl ^ (srow & 7);
  const int gsl  = (esl < 4) ? (2 * esl) : (2 * (esl & 3) + 1);
  const uint8_t* gA0 = xf8 + (size_t)(bm + srow) * DIM + gsl * 16;

#define GLL(srcp, dstoff)                                                        \
  __builtin_amdgcn_global_load_lds(                                              \
      (const __attribute__((address_space(1))) void*)(srcp),                     \
      (__attribute__((address_space(3))) void*)(smem + (dstoff)), 16, 0, 0)

  // stage A for step gidx into buffer (gidx&1)
#define STAGE(gidx)                                                              \
  { const int dk_ = ((gidx) & 3) * 128, b_ = ((gidx) & 1) * ABUF;                \
    _Pragma("unroll")                                                            \
    for (int cc = 0; cc < 4; ++cc)                                               \
      GLL(gA0 + (size_t)cc * 32 * DIM + dk_, b_ + cc * 4096 + w * 1024); }

  // A fragment read slots (zero-conflict pair, measured 0 in R10/R12)
  const int h   = l15 & 7;
  const int sl0 = (l4 ^ h) * 16;
  const int sl1 = sl0 ^ 64;
  int aoff[4];
  #pragma unroll
  for (int i = 0; i < 4; ++i)
    aoff[i] = (wr * 64 + i * 16 + l15) * 128;

  // B fragment pointers: row = colstart + wc*64 + ni*16 + l15, k-base = l4*32;
  // per-kt k advance via imm offset (kt*128 <= 384, fits 13-bit signed imm).
  const uint8_t* pB0 = rf8 + (size_t)(colstart + wc * 64 + 0 * 16 + l15) * DIM + l4 * 32;
  const uint8_t* pB1 = rf8 + (size_t)(colstart + wc * 64 + 1 * 16 + l15) * DIM + l4 * 32;
  const uint8_t* pB2 = rf8 + (size_t)(colstart + wc * 64 + 2 * 16 + l15) * DIM + l4 * 32;
  const uint8_t* pB3 = rf8 + (size_t)(colstart + wc * 64 + 3 * 16 + l15) * DIM + l4 * 32;

  // per-block row metadata, hoisted
  float x2v[16]; int yv[16];
  #pragma unroll
  for (int i = 0; i < 16; ++i) {
    int row = bm + wr * 64 + (i >> 2) * 16 + l4 * 4 + (i & 3);
    x2v[i] = cx2[row];
    yv[i]  = y[row];
  }

  float tot[16], mat[16];
  #pragma unroll
  for (int i = 0; i < 16; ++i) { tot[i] = 0.f; mat[i] = 0.f; }

  f32x4 acc[4][4];
  const f32x4 fz = {0.f, 0.f, 0.f, 0.f};
  float r2cP[4]; int clsP[4];                // epilogue metadata, prefetched @kt2

  // ---- prologue ----
  STAGE(0);
  asm volatile("s_waitcnt vmcnt(0)" ::: "memory");
  __builtin_amdgcn_s_barrier();

  #pragma unroll
  for (int g = 0; g < NSTEP; ++g) {
    const int kt = g & 3, ch = g >> 2;
    const int dkb = kt * 128;
    const int bofs = (g & 1) * ABUF;

    if (g + 1 < NSTEP) { STAGE(g + 1); }

    if (kt == 0) {
      #pragma unroll
      for (int mi = 0; mi < 4; ++mi)
        #pragma unroll
        for (int ni = 0; ni < 4; ++ni) acc[mi][ni] = fz;
    }
    if (kt == 2) {
      const int colb = colstart + ch * CHUNK;
      #pragma unroll
      for (int ni = 0; ni < 4; ++ni) {
        int cg = colb + wc * 64 + ni * 16 + l15;
        r2cP[ni] = cr2[cg];
        clsP[ni] = yref[cg];
      }
    }

    // B fragments direct from global (L2-hot slice); compiler waits vmcnt
    i32x8 bfr[4];
    {
      i32x4 lo, hi;
      lo = *(const i32x4*)(pB0 + dkb); hi = *(const i32x4*)(pB0 + dkb + 16);
      bfr[0] = __builtin_shufflevector(lo, hi, 0, 1, 2, 3, 4, 5, 6, 7);
      lo = *(const i32x4*)(pB1 + dkb); hi = *(const i32x4*)(pB1 + dkb + 16);
      bfr[1] = __builtin_shufflevector(lo, hi, 0, 1, 2, 3, 4, 5, 6, 7);
      lo = *(const i32x4*)(pB2 + dkb); hi = *(const i32x4*)(pB2 + dkb + 16);
      bfr[2] = __builtin_shufflevector(lo, hi, 0, 1, 2, 3, 4, 5, 6, 7);
      lo = *(const i32x4*)(pB3 + dkb); hi = *(const i32x4*)(pB3 + dkb + 16);
      bfr[3] = __builtin_shufflevector(lo, hi, 0, 1, 2, 3, 4, 5, 6, 7);
    }

    // A fragments from LDS buf
    const unsigned char* pS = smem + bofs;
    #pragma unroll
    for (int mi = 0; mi < 4; ++mi) {
      i32x4 lo = *(const i32x4*)(pS + aoff[mi] + sl0);
      i32x4 hi = *(const i32x4*)(pS + aoff[mi] + sl1);
      i32x8 afr = __builtin_shufflevector(lo, hi, 0, 1, 2, 3, 4, 5, 6, 7);
      #pragma unroll
      for (int ni = 0; ni < 4; ++ni)
        acc[mi][ni] = __builtin_amdgcn_mfma_scale_f32_16x16x128_f8f6f4(
            afr, bfr[ni], acc[mi][ni],
            0, 0,                      // cbsz=fp8(e4m3), blgp=fp8(e4m3)
            0, 0x7F7F7F7F,             // A scales = 1.0 (E8M0 127)
            0, 0x7F7F7F7F);            // B scales = 1.0
    }

    if (kt == 3) {
      // fused epilogue (chunk ch): e = exp2(-sqrt(cx2 + cr2 - 2c*dot));
      // sits between STAGE(g+1) issue and the drain -> hides A-stage HBM.
      #pragma unroll
      for (int mi = 0; mi < 4; ++mi) {
        #pragma unroll
        for (int r = 0; r < 4; ++r) {
          const int gi = mi * 4 + r;
          float xr = x2v[gi];
          int   yy = yv[gi];
          float tsum = 0.f, msum = 0.f;
          #pragma unroll
          for (int ni = 0; ni < 4; ++ni) {
            float t = fmaf(-2.0f * C_L2E2, acc[mi][ni][r], xr + r2cP[ni]);
            t = fmaxf(t, 0.0f);
            float d = __builtin_amdgcn_sqrtf(t);
            float e = __builtin_amdgcn_exp2f(-d);       // neg = free src modifier
            tsum += e;
            msum = fmaf(e, (clsP[ni] == yy) ? 1.0f : 0.0f, msum);
          }
          tot[gi] += tsum;
          mat[gi] += msum;
        }
      }
      // advance B pointers to next chunk
      pB0 += CHUNK * DIM; pB1 += CHUNK * DIM; pB2 += CHUNK * DIM; pB3 += CHUNK * DIM;
    }

    asm volatile("s_waitcnt vmcnt(0)" ::: "memory");
    __builtin_amdgcn_s_barrier();
  }

  // reduce across the 16 lanes (l15) sharing each row, then merge globally
  #pragma unroll
  for (int i = 0; i < 16; ++i) {
    float t = tot[i], m = mat[i];
    #pragma unroll
    for (int d = 1; d <= 8; d <<= 1) {
      t += __shfl_xor(t, d, 64);
      m += __shfl_xor(m, d, 64);
    }
    if (l15 == 0) {
      int row = bm + wr * 64 + (i >> 2) * 16 + l4 * 4 + (i & 3);
      atomicAdd(&totG[row], t);
      atomicAdd(&matchG[row], m);
    }
  }
#undef GLL
#undef STAGE
}

__global__ void finalize_loss(const float* __restrict__ totG, const float* __restrict__ matchG,
                              float* __restrict__ out) {
  __shared__ float red[256];
  int t = threadIdx.x;
  float s = 0.f;
  for (int r = t; r < M_ROWS; r += 256)
    s += logf(matchG[r] / totG[r] + 1e-6f);
  red[t] = s;
  __syncthreads();
  for (int off = 128; off >= 1; off >>= 1) {
    if (t < off) red[t] += red[t + off];
    __syncthreads();
  }
  if (t == 0) out[0] = -red[0] / (float)M_ROWS;
}

extern "C" void kernel_launch(void* const* d_in, const int* in_sizes, int n_in,
                              void* d_out, int out_size, void* d_ws, size_t ws_size,
                              hipStream_t stream) {
  const float* x    = (const float*)d_in[0];
  const float* xref = (const float*)d_in[1];
  const int*   y    = (const int*)d_in[2];
  const int*   yref = (const int*)d_in[3];
  float* out = (float*)d_out;

  uint8_t* ws = (uint8_t*)d_ws;
  uint8_t* xf8    = ws;                                 //  2 MB
  uint8_t* rf8    = ws + 2097152;                       // 16 MB
  float*   cx2    = (float*)(ws + 18874368);            // 16 KB (pre-scaled)
  float*   cr2    = (float*)(ws + 18890752);            // 128 KB (pre-scaled)
  float*   totG   = (float*)(ws + 19021824);            // 16 KB
  float*   matchG = (float*)(ws + 19038208);            // 16 KB

  hipMemsetAsync(totG, 0, 2 * M_ROWS * sizeof(float), stream);

  prep_all_fp8<<<M_ROWS + N_REFS, 256, 0, stream>>>(x, xref, xf8, rf8, cx2, cr2);
  ask_main<<<(M_ROWS / BM) * NSPLIT, 256, 0, stream>>>(xf8, rf8, cx2, cr2, y, yref, totG, matchG);
  finalize_loss<<<1, 256, 0, stream>>>(totG, matchG, out);
}